// Round 2
// baseline (34392.505 us; speedup 1.0000x reference)
//
#include <hip/hip_runtime.h>
#include <stdint.h>

#define NBLK 256
#define NTHR 512

typedef _Float16 f16;
typedef _Float16 f16x8 __attribute__((ext_vector_type(8)));
typedef float f32x4 __attribute__((ext_vector_type(4)));
typedef unsigned long long u64;

// ---------------- helpers ----------------

// 2-plane split (weights): w ~= hi + lo/2048, residual ~|w|*2^-22.
__device__ __forceinline__ void split2(float w, f16& hi, f16& lo) {
  f16 h = (__builtin_fabsf(w) < 6.104e-05f) ? (f16)0.0f : (f16)w;
  hi = h;
  lo = (f16)((w - (float)h) * 2048.0f);
}

// 3-plane split (activations): w ~= h + l/2^11 + m/2^22, residual ~|w|*2^-33.
// Denormal-guarded at every plane so MFMA denormal-flush (if any) is harmless.
__device__ __forceinline__ void split3(float w, f16& h, f16& l, f16& m) {
  const float hf = (__builtin_fabsf(w) < 6.104e-05f) ? 0.0f : (float)(f16)w;
  h = (f16)hf;
  const float r1s = (w - hf) * 2048.0f;
  const float lf = (__builtin_fabsf(r1s) < 6.104e-05f) ? 0.0f : (float)(f16)r1s;
  l = (f16)lf;
  const float r2s = (r1s - lf) * 2048.0f;
  m = (__builtin_fabsf(r2s) < 6.104e-05f) ? (f16)0.0f : (f16)r2s;
}

// fp32-sequence-mimicking sigmoid: e=fl32(exp(-z)); 1/fl32(1+e)
__device__ __forceinline__ float sig32(float z) {
  const float e32 = (float)exp(-(double)z);
  return 1.0f / __fadd_rn(1.0f, e32);
}
__device__ __forceinline__ float tanh32f(float z) { return (float)tanh((double)z); }

// Pack (value, col) into u64 so that u64-max == (max value, lowest col).
__device__ __forceinline__ u64 packvc(float v, unsigned col) {
  unsigned u = __float_as_uint(v);
  u = (u & 0x80000000u) ? ~u : (u | 0x80000000u);
  return ((u64)u << 32) | (u64)(0xFFFFFFFFu - col);
}
__device__ __forceinline__ u64 umax64(u64 a, u64 b) { return a > b ? a : b; }

// ---------------- param structs ----------------

struct MainP {
  const float* emb;
  const float* bias[4];
  const float* fcb;
  const float* hini[4];
  const float* cini[4];
  const f16* Whi[4];  // transposed concat [4096][K_l], K_0=1536 (Wx0|Wh0), else 2048
  const f16* Wlo[4];
  const f16* fchi;    // [32000][1024]
  const f16* fclo;
  f16* axh[5];        // activation plane hi: 0:[32][1024]; 1..3:[32][2048]; 4:[32][1024]
  f16* axl[5];        // plane lo  (2^-11)
  f16* axm[5];        // plane lo2 (2^-22)
  u64* top;           // [32][256]
  unsigned* bar;
  float* out;
};

struct PrepP {
  const float* src[9];
  f16* dhi[9];
  f16* dlo[9];
  int srcK[9];
  int srcN[9];
  int dstK[9];
  int koff[9];
  int base[9];
  unsigned* bar;
};

// ---------------- grid barrier ----------------

__device__ __forceinline__ void grid_barrier(unsigned* cnt, unsigned* gen) {
  __syncthreads();
  if (threadIdx.x == 0) {
    unsigned g = __hip_atomic_load(gen, __ATOMIC_RELAXED, __HIP_MEMORY_SCOPE_AGENT);
    unsigned prev = __hip_atomic_fetch_add(cnt, 1u, __ATOMIC_ACQ_REL, __HIP_MEMORY_SCOPE_AGENT);
    if (prev == (unsigned)(NBLK - 1)) {
      __hip_atomic_store(cnt, 0u, __ATOMIC_RELAXED, __HIP_MEMORY_SCOPE_AGENT);
      __hip_atomic_store(gen, g + 1u, __ATOMIC_RELEASE, __HIP_MEMORY_SCOPE_AGENT);
    } else {
      while (__hip_atomic_load(gen, __ATOMIC_RELAXED, __HIP_MEMORY_SCOPE_AGENT) == g) {
        __builtin_amdgcn_s_sleep(1);
      }
      __builtin_amdgcn_fence(__ATOMIC_ACQUIRE, "agent");
    }
  }
  __syncthreads();
}

// ---------------- prep: transpose + fp16 2-plane split of all weights ----------------

__global__ __launch_bounds__(256) void prep_split(PrepP p) {
  const int bid = blockIdx.x;
  const int tid = threadIdx.x;
  if (bid == 0 && tid == 0) { p.bar[0] = 0; p.bar[1] = 0; }

  int job = 0;
#pragma unroll
  for (int j2 = 1; j2 < 9; ++j2) job += (bid >= p.base[j2]) ? 1 : 0;
  const int tile = bid - p.base[job];
  const float* src = p.src[job];
  f16* dhi = p.dhi[job];
  f16* dlo = p.dlo[job];
  const int srcN = p.srcN[job];
  const int dstK = p.dstK[job];
  const int koff = p.koff[job];
  const int nK = p.srcK[job] >> 6;
  const int tk = tile % nK;
  const int tc = tile / nK;

  __shared__ float lds[64][65];
  {
    const int j = tid & 63, i0 = tid >> 6;
#pragma unroll
    for (int r = 0; r < 16; ++r) {
      const int i = r * 4 + i0;
      lds[i][j] = src[(size_t)(tk * 64 + i) * srcN + tc * 64 + j];
    }
  }
  __syncthreads();
  {
    const int jc = tid >> 2, part = tid & 3;
    f16x8 h0v, l0v, h1v, l1v;
#pragma unroll
    for (int ii = 0; ii < 8; ++ii) {
      f16 a, b;
      split2(lds[part * 16 + ii][jc], a, b);
      h0v[ii] = a; l0v[ii] = b;
    }
#pragma unroll
    for (int ii = 0; ii < 8; ++ii) {
      f16 a, b;
      split2(lds[part * 16 + 8 + ii][jc], a, b);
      h1v[ii] = a; l1v[ii] = b;
    }
    const size_t db = (size_t)(tc * 64 + jc) * dstK + koff + tk * 64 + part * 16;
    *(f16x8*)(dhi + db) = h0v;
    *(f16x8*)(dhi + db + 8) = h1v;
    *(f16x8*)(dlo + db) = l0v;
    *(f16x8*)(dlo + db + 8) = l1v;
  }
}

__global__ void ws_sentinel(float* out) {
  if (blockIdx.x == 0 && threadIdx.x == 0) out[0] = 1.0e9f;
}

// ---------------- main persistent kernel ----------------
// 256 blocks x 512 threads (8 waves). Block owns z-cols {1024g + 4*blk + j} of
// every LSTM layer and vocab cols [125*blk, 125*blk+125) of the FC.
// MFMA 16x16x32 f16: A row = lane&15, k = 8*(lane>>4)+t (contiguous, verified by
// m92/m97 ref-checked ladder); B col = lane&15; D col = lane&15, row = 4*(lane>>4)+reg.

__global__ __launch_bounds__(NTHR, 2) void lstm_main(MainP p) {
  const int blk = blockIdx.x;
  const int tid = threadIdx.x;
  const int lane = tid & 63;
  const int w = tid >> 6;
  const int q = lane >> 4;
  const int n16 = lane & 15;

  __shared__ float zpart[8][2][32][16];  // per-wave partials, bucket 0 = x@Wx, 1 = h@Wh
  __shared__ float fcpart[2][32][128];   // FC K-half partials
  __shared__ float zred[32][16];         // final fp32 z
  __shared__ float cst[4][32][4];        // c state
  __shared__ f16 hs_h[32][4];            // pending recurrent-state write (3 planes)
  __shared__ f16 hs_l[32][4];
  __shared__ f16 hs_m[32][4];
  __shared__ int tokS[32];
  __shared__ u64 redu[32][16];

  unsigned* bcnt = p.bar;
  unsigned* bgen = p.bar + 1;

  // ---- init: c state + initial h split3 into state halves ----
  for (int i = tid; i < 512; i += NTHR) {
    const int l = i >> 7, b = (i >> 2) & 31, j = i & 3;
    cst[l][b][j] = p.cini[l][b * 1024 + 4 * blk + j];
    f16 hh, ll, mm;
    split3(p.hini[l][b * 1024 + 4 * blk + j], hh, ll, mm);
    if (l == 0) {
      p.axh[0][b * 1024 + 4 * blk + j] = hh;
      p.axl[0][b * 1024 + 4 * blk + j] = ll;
      p.axm[0][b * 1024 + 4 * blk + j] = mm;
    } else {
      p.axh[l][b * 2048 + 1024 + 4 * blk + j] = hh;
      p.axl[l][b * 2048 + 1024 + 4 * blk + j] = ll;
      p.axm[l][b * 2048 + 1024 + 4 * blk + j] = mm;
    }
  }
  grid_barrier(bcnt, bgen);

  const int col16 = 1024 * (n16 >> 2) + 4 * blk + (n16 & 3);

  // gate math + state update + below-half activation write for layer l
  auto layer_tail = [&](int l, const float* bias, f16* dh, f16* dl, f16* dm, int dstride) {
    __syncthreads();
    {
      const int row = tid >> 4, c = tid & 15;
      double A = 0.0, B = 0.0;
#pragma unroll
      for (int w2 = 0; w2 < 8; ++w2) {
        A += (double)zpart[w2][0][row][c];
        B += (double)zpart[w2][1][row][c];
      }
      // mimic np: fl32( fl32(x@Wx + h@Wh) + b )
      zred[row][c] = __fadd_rn(__fadd_rn((float)A, (float)B),
                               bias[1024 * (c >> 2) + 4 * blk + (c & 3)]);
    }
    __syncthreads();
    if (tid < 128) {
      const int b = tid >> 2, j = tid & 3;
      const float zi = zred[b][j], zf = zred[b][4 + j], zg = zred[b][8 + j], zo = zred[b][12 + j];
      const float i_ = sig32(zi);
      const float f_ = sig32(zf);
      const float g_ = tanh32f(zg);
      const float o_ = sig32(zo);
      const float c_ = __fadd_rn(__fmul_rn(f_, cst[l][b][j]), __fmul_rn(i_, g_));
      cst[l][b][j] = c_;
      const float h_ = __fmul_rn(o_, tanh32f(c_));
      f16 hh, ll, mm;
      split3(h_, hh, ll, mm);
      hs_h[b][j] = hh; hs_l[b][j] = ll; hs_m[b][j] = mm;
      dh[b * dstride + 4 * blk + j] = hh;
      dl[b * dstride + 4 * blk + j] = ll;
      dm[b * dstride + 4 * blk + j] = mm;
    }
  };

  for (int t = 0; t < 128; ++t) {
    // ========== PHASE A: decide token ==========
    if (t == 0) {
      if (tid < 32) tokS[tid] = 1;  // START
    } else {
      const int row = tid >> 4, seg = tid & 15;
      const u64* tr = p.top + row * 256 + seg * 16;
      u64 m = 0;
#pragma unroll
      for (int e = 0; e < 16; ++e) m = umax64(m, tr[e]);
      redu[row][seg] = m;
      __syncthreads();
      if (tid < 32) {
        u64 mm = redu[tid][0];
#pragma unroll
        for (int s2 = 1; s2 < 16; ++s2) mm = umax64(mm, redu[tid][s2]);
        const int tok = (int)(0xFFFFFFFFu - (unsigned)(mm & 0xFFFFFFFFull));
        tokS[tid] = tok;
        if (blk == tid)
          p.out[(size_t)32 * 128 * 32000 + (size_t)tid * 128 + (t - 1)] = (float)tok;
      }
    }
    __syncthreads();

    // ========== layer 0: K = 1536 (emb 512 | h0-state 1024) ==========
    {
      double zdA0[4] = {0,0,0,0}, zdA1[4] = {0,0,0,0};  // emb bucket, rowtiles 0/1
      double zdB0[4] = {0,0,0,0}, zdB1[4] = {0,0,0,0};  // state bucket
      const size_t wrow = (size_t)col16 * 1536;
      const f32x4 zz = {0.f, 0.f, 0.f, 0.f};
#pragma unroll
      for (int sl = 0; sl < 6; ++sl) {
        const int k0 = (w * 6 + sl) * 32 + 8 * q;
        const f16x8 bh = *(const f16x8*)(p.Whi[0] + wrow + k0);
        const f16x8 bl = *(const f16x8*)(p.Wlo[0] + wrow + k0);
        f16x8 ah0, al0, am0, ah1, al1, am1;
        if (k0 < 512) {
          {
            const float* ep = p.emb + (size_t)tokS[n16] * 512 + k0;
            const float4 v0 = *(const float4*)ep;
            const float4 v1 = *(const float4*)(ep + 4);
            const float vv[8] = {v0.x, v0.y, v0.z, v0.w, v1.x, v1.y, v1.z, v1.w};
#pragma unroll
            for (int e = 0; e < 8; ++e) { f16 a,b,c; split3(vv[e],a,b,c); ah0[e]=a; al0[e]=b; am0[e]=c; }
          }
          {
            const float* ep = p.emb + (size_t)tokS[16 + n16] * 512 + k0;
            const float4 v0 = *(const float4*)ep;
            const float4 v1 = *(const float4*)(ep + 4);
            const float vv[8] = {v0.x, v0.y, v0.z, v0.w, v1.x, v1.y, v1.z, v1.w};
#pragma unroll
            for (int e = 0; e < 8; ++e) { f16 a,b,c; split3(vv[e],a,b,c); ah1[e]=a; al1[e]=b; am1[e]=c; }
          }
        } else {
          const int ks = k0 - 512;
          ah0 = *(const f16x8*)(p.axh[0] + n16 * 1024 + ks);
          al0 = *(const f16x8*)(p.axl[0] + n16 * 1024 + ks);
          am0 = *(const f16x8*)(p.axm[0] + n16 * 1024 + ks);
          ah1 = *(const f16x8*)(p.axh[0] + (16 + n16) * 1024 + ks);
          al1 = *(const f16x8*)(p.axl[0] + (16 + n16) * 1024 + ks);
          am1 = *(const f16x8*)(p.axm[0] + (16 + n16) * 1024 + ks);
        }
        f32x4 t00 = __builtin_amdgcn_mfma_f32_16x16x32_f16(ah0, bh, zz, 0, 0, 0);
        f32x4 t10 = __builtin_amdgcn_mfma_f32_16x16x32_f16(ah0, bl, zz, 0, 0, 0);
        t10 = __builtin_amdgcn_mfma_f32_16x16x32_f16(al0, bh, t10, 0, 0, 0);
        f32x4 t20 = __builtin_amdgcn_mfma_f32_16x16x32_f16(al0, bl, zz, 0, 0, 0);
        t20 = __builtin_amdgcn_mfma_f32_16x16x32_f16(am0, bh, t20, 0, 0, 0);
        f32x4 t01 = __builtin_amdgcn_mfma_f32_16x16x32_f16(ah1, bh, zz, 0, 0, 0);
        f32x4 t11 = __builtin_amdgcn_mfma_f32_16x16x32_f16(ah1, bl, zz, 0, 0, 0);
        t11 = __builtin_amdgcn_mfma_f32_16x16x32_f16(al1, bh, t11, 0, 0, 0);
        f32x4 t21 = __builtin_amdgcn_mfma_f32_16x16x32_f16(al1, bl, zz, 0, 0, 0);
        t21 = __builtin_amdgcn_mfma_f32_16x16x32_f16(am1, bh, t21, 0, 0, 0);
        if (k0 < 512) {
#pragma unroll
          for (int r = 0; r < 4; ++r) {
            zdA0[r] += (double)t00[r] + (double)t10[r] * 0x1p-11 + (double)t20[r] * 0x1p-22;
            zdA1[r] += (double)t01[r] + (double)t11[r] * 0x1p-11 + (double)t21[r] * 0x1p-22;
          }
        } else {
#pragma unroll
          for (int r = 0; r < 4; ++r) {
            zdB0[r] += (double)t00[r] + (double)t10[r] * 0x1p-11 + (double)t20[r] * 0x1p-22;
            zdB1[r] += (double)t01[r] + (double)t11[r] * 0x1p-11 + (double)t21[r] * 0x1p-22;
          }
        }
      }
#pragma unroll
      for (int r = 0; r < 4; ++r) {
        zpart[w][0][4 * q + r][n16] = (float)zdA0[r];
        zpart[w][0][16 + 4 * q + r][n16] = (float)zdA1[r];
        zpart[w][1][4 * q + r][n16] = (float)zdB0[r];
        zpart[w][1][16 + 4 * q + r][n16] = (float)zdB1[r];
      }
    }
    layer_tail(0, p.bias[0], p.axh[1], p.axl[1], p.axm[1], 2048);
    grid_barrier(bcnt, bgen);

    // ========== layers 1..3 ==========
    for (int l = 1; l < 4; ++l) {
      if (tid < 128) {  // deferred recurrent-state write of h_{l-1}(t)
        const int b = tid >> 2, j = tid & 3;
        if (l == 1) {
          p.axh[0][b * 1024 + 4 * blk + j] = hs_h[b][j];
          p.axl[0][b * 1024 + 4 * blk + j] = hs_l[b][j];
          p.axm[0][b * 1024 + 4 * blk + j] = hs_m[b][j];
        } else {
          p.axh[l - 1][b * 2048 + 1024 + 4 * blk + j] = hs_h[b][j];
          p.axl[l - 1][b * 2048 + 1024 + 4 * blk + j] = hs_l[b][j];
          p.axm[l - 1][b * 2048 + 1024 + 4 * blk + j] = hs_m[b][j];
        }
      }
      {
        double zdA0[4] = {0,0,0,0}, zdA1[4] = {0,0,0,0};
        double zdB0[4] = {0,0,0,0}, zdB1[4] = {0,0,0,0};
        const f16* Whi_ = p.Whi[l];
        const f16* Wlo_ = p.Wlo[l];
        const f16* axh_ = p.axh[l];
        const f16* axl_ = p.axl[l];
        const f16* axm_ = p.axm[l];
        const size_t wrow = (size_t)col16 * 2048;
        const f32x4 zz = {0.f, 0.f, 0.f, 0.f};
#pragma unroll
        for (int sl = 0; sl < 8; ++sl) {
          const int k0 = (w * 8 + sl) * 32 + 8 * q;
          const f16x8 bh = *(const f16x8*)(Whi_ + wrow + k0);
          const f16x8 bl = *(const f16x8*)(Wlo_ + wrow + k0);
          const f16x8 ah0 = *(const f16x8*)(axh_ + n16 * 2048 + k0);
          const f16x8 al0 = *(const f16x8*)(axl_ + n16 * 2048 + k0);
          const f16x8 am0 = *(const f16x8*)(axm_ + n16 * 2048 + k0);
          const f16x8 ah1 = *(const f16x8*)(axh_ + (16 + n16) * 2048 + k0);
          const f16x8 al1 = *(const f16x8*)(axl_ + (16 + n16) * 2048 + k0);
          const f16x8 am1 = *(const f16x8*)(axm_ + (16 + n16) * 2048 + k0);
          f32x4 t00 = __builtin_amdgcn_mfma_f32_16x16x32_f16(ah0, bh, zz, 0, 0, 0);
          f32x4 t10 = __builtin_amdgcn_mfma_f32_16x16x32_f16(ah0, bl, zz, 0, 0, 0);
          t10 = __builtin_amdgcn_mfma_f32_16x16x32_f16(al0, bh, t10, 0, 0, 0);
          f32x4 t20 = __builtin_amdgcn_mfma_f32_16x16x32_f16(al0, bl, zz, 0, 0, 0);
          t20 = __builtin_amdgcn_mfma_f32_16x16x32_f16(am0, bh, t20, 0, 0, 0);
          f32x4 t01 = __builtin_amdgcn_mfma_f32_16x16x32_f16(ah1, bh, zz, 0, 0, 0);
          f32x4 t11 = __builtin_amdgcn_mfma_f32_16x16x32_f16(ah1, bl, zz, 0, 0, 0);
          t11 = __builtin_amdgcn_mfma_f32_16x16x32_f16(al1, bh, t11, 0, 0, 0);
          f32x4 t21 = __builtin_amdgcn_mfma_f32_16x16x32_f16(al1, bl, zz, 0, 0, 0);
          t21 = __builtin_amdgcn_mfma_f32_16x16x32_f16(am1, bh, t21, 0, 0, 0);
          if (k0 < 1024) {
#pragma unroll
            for (int r = 0; r < 4; ++r) {
              zdA0[r] += (double)t00[r] + (double)t10[r] * 0x1p-11 + (double)t20[r] * 0x1p-22;
              zdA1[r] += (double)t01[r] + (double)t11[r] * 0x1p-11 + (double)t21[r] * 0x1p-22;
            }
          } else {
#pragma unroll
            for (int r = 0; r < 4; ++r) {
              zdB0[r] += (double)t00[r] + (double)t10[r] * 0x1p-11 + (double)t20[r] * 0x1p-22;
              zdB1[r] += (double)t01[r] + (double)t11[r] * 0x1p-11 + (double)t21[r] * 0x1p-22;
            }
          }
        }
#pragma unroll
        for (int r = 0; r < 4; ++r) {
          zpart[w][0][4 * q + r][n16] = (float)zdA0[r];
          zpart[w][0][16 + 4 * q + r][n16] = (float)zdA1[r];
          zpart[w][1][4 * q + r][n16] = (float)zdB0[r];
          zpart[w][1][16 + 4 * q + r][n16] = (float)zdB1[r];
        }
      }
      if (l < 3) layer_tail(l, p.bias[l], p.axh[l + 1], p.axl[l + 1], p.axm[l + 1], 2048);
      else       layer_tail(l, p.bias[l], p.axh[4], p.axl[4], p.axm[4], 1024);
      grid_barrier(bcnt, bgen);
    }

    // ========== PHASE E: FC + local argmax ==========
    if (tid < 128) {  // deferred h3(t) state write
      const int b = tid >> 2, j = tid & 3;
      p.axh[3][b * 2048 + 1024 + 4 * blk + j] = hs_h[b][j];
      p.axl[3][b * 2048 + 1024 + 4 * blk + j] = hs_l[b][j];
      p.axm[3][b * 2048 + 1024 + 4 * blk + j] = hs_m[b][j];
    }
    {
      const int kh = w & 1;
      const int tg = w >> 1;
      double LdA0[4] = {0,0,0,0}, LdA1[4] = {0,0,0,0};
      double LdB0[4] = {0,0,0,0}, LdB1[4] = {0,0,0,0};
      const int clA = (tg * 2 + 0) * 16 + n16;
      const int clB = (tg * 2 + 1) * 16 + n16;
      const size_t fbA = (size_t)(125 * blk + (clA < 125 ? clA : 124)) * 1024;
      const size_t fbB = (size_t)(125 * blk + (clB < 125 ? clB : 124)) * 1024;
      const f32x4 zz = {0.f, 0.f, 0.f, 0.f};
#pragma unroll
      for (int sl = 0; sl < 16; ++sl) {
        const int k0 = (kh * 16 + sl) * 32 + 8 * q;
        const f16x8 ah0 = *(const f16x8*)(p.axh[4] + n16 * 1024 + k0);
        const f16x8 al0 = *(const f16x8*)(p.axl[4] + n16 * 1024 + k0);
        const f16x8 am0 = *(const f16x8*)(p.axm[4] + n16 * 1024 + k0);
        const f16x8 ah1 = *(const f16x8*)(p.axh[4] + (16 + n16) * 1024 + k0);
        const f16x8 al1 = *(const f16x8*)(p.axl[4] + (16 + n16) * 1024 + k0);
        const f16x8 am1 = *(const f16x8*)(p.axm[4] + (16 + n16) * 1024 + k0);
        {
          const f16x8 bh = *(const f16x8*)(p.fchi + fbA + k0);
          const f16x8 bl = *(const f16x8*)(p.fclo + fbA + k0);
          f32x4 t00 = __builtin_amdgcn_mfma_f32_16x16x32_f16(ah0, bh, zz, 0, 0, 0);
          f32x4 t10 = __builtin_amdgcn_mfma_f32_16x16x32_f16(ah0, bl, zz, 0, 0, 0);
          t10 = __builtin_amdgcn_mfma_f32_16x16x32_f16(al0, bh, t10, 0, 0, 0);
          f32x4 t20 = __builtin_amdgcn_mfma_f32_16x16x32_f16(al0, bl, zz, 0, 0, 0);
          t20 = __builtin_amdgcn_mfma_f32_16x16x32_f16(am0, bh, t20, 0, 0, 0);
          f32x4 t01 = __builtin_amdgcn_mfma_f32_16x16x32_f16(ah1, bh, zz, 0, 0, 0);
          f32x4 t11 = __builtin_amdgcn_mfma_f32_16x16x32_f16(ah1, bl, zz, 0, 0, 0);
          t11 = __builtin_amdgcn_mfma_f32_16x16x32_f16(al1, bh, t11, 0, 0, 0);
          f32x4 t21 = __builtin_amdgcn_mfma_f32_16x16x32_f16(al1, bl, zz, 0, 0, 0);
          t21 = __builtin_amdgcn_mfma_f32_16x16x32_f16(am1, bh, t21, 0, 0, 0);
#pragma unroll
          for (int r = 0; r < 4; ++r) {
            LdA0[r] += (double)t00[r] + (double)t10[r] * 0x1p-11 + (double)t20[r] * 0x1p-22;
            LdA1[r] += (double)t01[r] + (double)t11[r] * 0x1p-11 + (double)t21[r] * 0x1p-22;
          }
        }
        {
          const f16x8 bh = *(const f16x8*)(p.fchi + fbB + k0);
          const f16x8 bl = *(const f16x8*)(p.fclo + fbB + k0);
          f32x4 t00 = __builtin_amdgcn_mfma_f32_16x16x32_f16(ah0, bh, zz, 0, 0, 0);
          f32x4 t10 = __builtin_amdgcn_mfma_f32_16x16x32_f16(ah0, bl, zz, 0, 0, 0);
          t10 = __builtin_amdgcn_mfma_f32_16x16x32_f16(al0, bh, t10, 0, 0, 0);
          f32x4 t20 = __builtin_amdgcn_mfma_f32_16x16x32_f16(al0, bl, zz, 0, 0, 0);
          t20 = __builtin_amdgcn_mfma_f32_16x16x32_f16(am0, bh, t20, 0, 0, 0);
          f32x4 t01 = __builtin_amdgcn_mfma_f32_16x16x32_f16(ah1, bh, zz, 0, 0, 0);
          f32x4 t11 = __builtin_amdgcn_mfma_f32_16x16x32_f16(ah1, bl, zz, 0, 0, 0);
          t11 = __builtin_amdgcn_mfma_f32_16x16x32_f16(al1, bh, t11, 0, 0, 0);
          f32x4 t21 = __builtin_amdgcn_mfma_f32_16x16x32_f16(al1, bl, zz, 0, 0, 0);
          t21 = __builtin_amdgcn_mfma_f32_16x16x32_f16(am1, bh, t21, 0, 0, 0);
#pragma unroll
          for (int r = 0; r < 4; ++r) {
            LdB0[r] += (double)t00[r] + (double)t10[r] * 0x1p-11 + (double)t20[r] * 0x1p-22;
            LdB1[r] += (double)t01[r] + (double)t11[r] * 0x1p-11 + (double)t21[r] * 0x1p-22;
          }
        }
      }
#pragma unroll
      for (int r = 0; r < 4; ++r) {
        fcpart[kh][4 * q + r][(tg * 2 + 0) * 16 + n16] = (float)LdA0[r];
        fcpart[kh][16 + 4 * q + r][(tg * 2 + 0) * 16 + n16] = (float)LdA1[r];
        fcpart[kh][4 * q + r][(tg * 2 + 1) * 16 + n16] = (float)LdB0[r];
        fcpart[kh][16 + 4 * q + r][(tg * 2 + 1) * 16 + n16] = (float)LdB1[r];
      }
    }
    __syncthreads();
    {
      const int row = tid >> 4, cg = tid & 15;
      u64 best = 0;
      float* orow = p.out + (size_t)row * (128 * 32000) + (size_t)t * 32000 + 125 * blk;
      const float* fb = p.fcb + 125 * blk;
#pragma unroll
      for (int cc = 0; cc < 8; ++cc) {
        const int c = cg * 8 + cc;
        if (c < 125) {
          const float z32 = (float)((double)fcpart[0][row][c] + (double)fcpart[1][row][c]);
          const float z = __fadd_rn(z32, fb[c]);
          __builtin_nontemporal_store(z, orow + c);
          best = umax64(best, packvc(z, (unsigned)(125 * blk + c)));
        }
      }
      redu[row][cg] = best;
    }
    __syncthreads();
    if (tid < 32) {
      u64 mm = redu[tid][0];
#pragma unroll
      for (int s2 = 1; s2 < 16; ++s2) mm = umax64(mm, redu[tid][s2]);
      p.top[tid * 256 + blk] = mm;
    }
    grid_barrier(bcnt, bgen);
  }

  // tail: token for t = 127
  if (blk < 32) {
    if (tid < 16) {
      const u64* tr = p.top + blk * 256 + tid * 16;
      u64 m = 0;
#pragma unroll
      for (int e = 0; e < 16; ++e) m = umax64(m, tr[e]);
      redu[0][tid] = m;
    }
    __syncthreads();
    if (tid == 0) {
      u64 mm = redu[0][0];
#pragma unroll
      for (int s2 = 1; s2 < 16; ++s2) mm = umax64(mm, redu[0][s2]);
      p.out[(size_t)32 * 128 * 32000 + (size_t)blk * 128 + 127] =
          (float)(0xFFFFFFFFu - (unsigned)(mm & 0xFFFFFFFFull));
    }
  }
}

// ---------------- host ----------------

extern "C" void kernel_launch(void* const* d_in, const int* in_sizes, int n_in,
                              void* d_out, int out_size, void* d_ws, size_t ws_size,
                              hipStream_t stream) {
  (void)in_sizes; (void)n_in; (void)out_size;
  const float* hini[4] = {(const float*)d_in[0], (const float*)d_in[2], (const float*)d_in[4], (const float*)d_in[6]};
  const float* cini[4] = {(const float*)d_in[1], (const float*)d_in[3], (const float*)d_in[5], (const float*)d_in[7]};
  const float* emb = (const float*)d_in[8];
  const float* Wx[4] = {(const float*)d_in[9], (const float*)d_in[12], (const float*)d_in[15], (const float*)d_in[18]};
  const float* Wh[4] = {(const float*)d_in[10], (const float*)d_in[13], (const float*)d_in[16], (const float*)d_in[19]};
  const float* bias[4] = {(const float*)d_in[11], (const float*)d_in[14], (const float*)d_in[17], (const float*)d_in[20]};
  const float* fcW = (const float*)d_in[21];
  const float* fcb = (const float*)d_in[22];

  char* ws = (char*)d_ws;
  size_t off = 0;
  auto take = [&](size_t bytes) -> char* {
    char* r = ws + off;
    off += (bytes + 255) & ~(size_t)255;
    return r;
  };
  f16* Whi[4]; f16* Wlo[4];
  Whi[0] = (f16*)take((size_t)4096 * 1536 * 2);
  Wlo[0] = (f16*)take((size_t)4096 * 1536 * 2);
  for (int l = 1; l < 4; ++l) {
    Whi[l] = (f16*)take((size_t)4096 * 2048 * 2);
    Wlo[l] = (f16*)take((size_t)4096 * 2048 * 2);
  }
  f16* fchi = (f16*)take((size_t)32000 * 1024 * 2);
  f16* fclo = (f16*)take((size_t)32000 * 1024 * 2);
  f16* axh[5]; f16* axl[5]; f16* axm[5];
  const int axsz[5] = {1024, 2048, 2048, 2048, 1024};
  for (int l = 0; l < 5; ++l) {
    axh[l] = (f16*)take((size_t)32 * axsz[l] * 2);
    axl[l] = (f16*)take((size_t)32 * axsz[l] * 2);
    axm[l] = (f16*)take((size_t)32 * axsz[l] * 2);
  }
  u64* top = (u64*)take((size_t)32 * 256 * 8);
  unsigned* bar = (unsigned*)take(256);

  if (off > ws_size) {
    hipLaunchKernelGGL(ws_sentinel, dim3(1), dim3(1), 0, stream, (float*)d_out);
    return;
  }

  PrepP pp;
  pp.src[0] = Wx[0]; pp.src[1] = Wh[0]; pp.src[2] = Wx[1]; pp.src[3] = Wh[1];
  pp.src[4] = Wx[2]; pp.src[5] = Wh[2]; pp.src[6] = Wx[3]; pp.src[7] = Wh[3];
  pp.src[8] = fcW;
  const int dj[8] = {0, 0, 1, 1, 2, 2, 3, 3};
  for (int j = 0; j < 8; ++j) { pp.dhi[j] = Whi[dj[j]]; pp.dlo[j] = Wlo[dj[j]]; }
  pp.dhi[8] = fchi; pp.dlo[8] = fclo;
  const int srcK[9] = {512, 1024, 1024, 1024, 1024, 1024, 1024, 1024, 1024};
  const int srcN[9] = {4096, 4096, 4096, 4096, 4096, 4096, 4096, 4096, 32000};
  const int dstK[9] = {1536, 1536, 2048, 2048, 2048, 2048, 2048, 2048, 1024};
  const int koff[9] = {0, 512, 0, 1024, 0, 1024, 0, 1024, 0};
  const int base[9] = {0, 512, 1536, 2560, 3584, 4608, 5632, 6656, 7680};
  for (int j = 0; j < 9; ++j) {
    pp.srcK[j] = srcK[j]; pp.srcN[j] = srcN[j]; pp.dstK[j] = dstK[j];
    pp.koff[j] = koff[j]; pp.base[j] = base[j];
  }
  pp.bar = bar;
  hipLaunchKernelGGL(prep_split, dim3(15680), dim3(256), 0, stream, pp);

  MainP mp;
  mp.emb = emb;
  for (int l = 0; l < 4; ++l) {
    mp.bias[l] = bias[l]; mp.hini[l] = hini[l]; mp.cini[l] = cini[l];
    mp.Whi[l] = Whi[l]; mp.Wlo[l] = Wlo[l];
  }
  mp.fcb = fcb; mp.fchi = fchi; mp.fclo = fclo;
  for (int l = 0; l < 5; ++l) { mp.axh[l] = axh[l]; mp.axl[l] = axl[l]; mp.axm[l] = axm[l]; }
  mp.top = top; mp.bar = bar; mp.out = (float*)d_out;

  void* args[] = {&mp};
  hipLaunchCooperativeKernel((void*)lstm_main, dim3(NBLK), dim3(NTHR), args, 0, stream);
}